// Round 16
// baseline (525.610 us; speedup 1.0000x reference)
//
#include <hip/hip_runtime.h>
#include <hip/hip_bf16.h>

#define T_DIM   2048
#define B_DIM   64
#define IN_DIM  256
#define H_DIM   256
#define M_TOT   (T_DIM * B_DIM)              // 131072
#define OUT_MAIN ((size_t)M_TOT * H_DIM)     // 33554432

typedef __bf16 bf16x8 __attribute__((ext_vector_type(8)));
typedef float  floatx4 __attribute__((ext_vector_type(4)));

__device__ __forceinline__ unsigned short f2bf(float f) {
    unsigned int u = __float_as_uint(f);
    unsigned int r = u + 0x7FFFu + ((u >> 16) & 1u);
    return (unsigned short)(r >> 16);
}
__device__ __forceinline__ float sigf(float v) {
    return 1.0f / (1.0f + __expf(-v));
}

// ---------------------------------------------------------------------------
// Prep: ghpack[b][h] = {gh_r + b_ih_r, gh_z + b_ih_z, gh_n, hid[b][h]}
//       wsA = w_ih bf16 swizzled into MFMA 16x16x32 A-fragment order
//             (lane&15 -> row n, (lane>>4)*8+j -> k), entry idx
//             ((ntile*8 + kstep)*64 + lane)*8
//       biasn[h] = b_ih[2H + h]
// ---------------------------------------------------------------------------
__global__ void __launch_bounds__(256) gru_prep(
    const float* __restrict__ hid, const float* __restrict__ w_ih,
    const float* __restrict__ w_hh, const float* __restrict__ b_ih,
    const float* __restrict__ b_hh, unsigned short* __restrict__ wsA,
    float4* __restrict__ ghpack, float* __restrict__ biasn)
{
    const int blk = blockIdx.x, tid = threadIdx.x;
    if (blk < 64) {
        const int bb = blk, h = tid;
        const float4* hv4 = (const float4*)(hid + (size_t)bb * H_DIM);
        const float4* w0  = (const float4*)(w_hh + (size_t)h * H_DIM);
        const float4* w1  = (const float4*)(w_hh + (size_t)(H_DIM + h) * H_DIM);
        const float4* w2  = (const float4*)(w_hh + (size_t)(2 * H_DIM + h) * H_DIM);
        float s0 = 0.f, s1 = 0.f, s2 = 0.f;
        for (int k = 0; k < H_DIM / 4; k++) {
            float4 hv = hv4[k];
            float4 a = w0[k]; s0 += hv.x*a.x + hv.y*a.y + hv.z*a.z + hv.w*a.w;
            float4 b = w1[k]; s1 += hv.x*b.x + hv.y*b.y + hv.z*b.z + hv.w*b.w;
            float4 c = w2[k]; s2 += hv.x*c.x + hv.y*c.y + hv.z*c.z + hv.w*c.w;
        }
        float4 o;
        o.x = s0 + b_hh[h]             + b_ih[h];
        o.y = s1 + b_hh[H_DIM + h]     + b_ih[H_DIM + h];
        o.z = s2 + b_hh[2 * H_DIM + h];
        o.w = hid[(size_t)bb * H_DIM + h];
        ghpack[bb * H_DIM + h] = o;
    } else if (blk < 160) {
        const int idx   = (blk - 64) * 256 + tid;   // 0..24575
        const int lane  = idx & 63;
        const int kstep = (idx >> 6) & 7;
        const int ntile = idx >> 9;                 // 0..47 over N=768
        const int n = ntile * 16 + (lane & 15);
        const int k = kstep * 32 + (lane >> 4) * 8;
        const float* src = w_ih + (size_t)n * IN_DIM + k;
        unsigned short* dst = wsA + (size_t)idx * 8;
        #pragma unroll
        for (int j = 0; j < 8; j++) dst[j] = f2bf(src[j]);
    } else {
        biasn[tid] = b_ih[2 * H_DIM + tid];
    }
}

// ---------------------------------------------------------------------------
// Main v3: weights live in LDS (24 KB/block), NOT registers.
//
// MEASURED rounds 5/9/14: hipcc refuses to keep the 96-VGPR invariant
// weight set resident (VGPR pinned at 84 across plain bounds, (256,2),
// and asm-laundered pins; FETCH byte-identical -> it remats the 24 wsA
// loads from L2 every iteration, ~200cy each, serialized -> 295-500 us).
// FIX: align with the compiler instead of fighting it. Waves in a block
// now share ONE 16-h group (split b across waves, not h) -> block weight
// set = 3 gates x 8 ksteps x 1 KB = 24 KB, staged to LDS once. The
// compiler's preferred per-iteration reload becomes ds_read_b128 (~12cy,
// no vmcnt, no L2 traffic) instead of global L2 loads.
//
// Block: 256 thr = 4 waves; wave wid owns b-quarter wid, all waves same
// hg (16 h) and same t. Grid: 64 tch x 16 hg = 1024 blocks, XCD-swizzled
// (16 hg-blocks sharing a tch's x slice land on one XCD's L2 -> measured
// round 5: FETCH 70 MB << 128 MB logical, sharing works).
// No in-loop barriers: waves share only read-only LDS after one sync.
// C/D per gate: col=lane&15 -> b-row, row=(lane>>4)*4+reg -> h.
// __launch_bounds__(256,4): cap 128 VGPR (live set ~110), target 4
// waves/EU -> 2x the occupancy of rounds 9/14.
// ---------------------------------------------------------------------------
__global__ void __launch_bounds__(256, 4) gru_main(
    const float* __restrict__ x, const unsigned short* __restrict__ wsA,
    const float4* __restrict__ ghpack, const float* __restrict__ biasn,
    float* __restrict__ out)
{
    __shared__ float4 wl4[1536];                   // 24576 B: [g][ks][lane]
    __shared__ float  epi[4][16 * 20];             // 5120 B, per-wave transpose

    const int tid  = threadIdx.x;
    const int lane = tid & 63;
    const int wid  = tid >> 6;                     // 0..3 = b-quarter
    const int lr = lane & 15, lq = lane >> 4;

    // XCD-contiguous: consecutive wg share tch -> same XCD L2 chunk.
    const int raw = blockIdx.x;
    const int wg  = (raw & 7) * 128 + (raw >> 3);  // 0..1023, bijective
    const int tch = wg >> 4;                       // 0..63, 32 t each
    const int hg  = wg & 15;                       // 0..15, 16 h each
    const int hbase = hg * 16;

    // ---- stage this hg's weight fragments into LDS (24 KB, once)
    {
        const float4* src4 = reinterpret_cast<const float4*>(wsA);
        #pragma unroll
        for (int j = 0; j < 6; j++) {
            const int idx = j * 256 + tid;         // 0..1535
            const int g = idx >> 9, rem = idx & 511;
            wl4[idx] = src4[((size_t)(g * 16 + hg)) * 512 + rem];
        }
    }
    // ---- per-(b,h) GRU state, fixed for whole block: b = wid*16+lr
    const floatx4* gh4 = reinterpret_cast<const floatx4*>(ghpack);
    floatx4 gp[4]; float bn[4];
    #pragma unroll
    for (int reg = 0; reg < 4; reg++) {
        gp[reg] = gh4[(wid * 16 + lr) * H_DIM + hbase + lq * 4 + reg];
        bn[reg] = biasn[hbase + lq * 4 + reg];
    }
    __syncthreads();

    const bf16x8* wlp = reinterpret_cast<const bf16x8*>(wl4) + lane;

    // lane's fixed x position: row b = wid*16+lr, col k = lq*8
    const float* xbase = x + ((size_t)wid * 16 + lr) * IN_DIM + lq * 8;

    #pragma unroll 1
    for (int i = 0; i < 32; i++) {
        const int t = tch * 32 + i;
        const float* xp = xbase + (size_t)t * (B_DIM * IN_DIM);

        // ---- issue all 16 x loads first (independent, pipelined)
        float4 xf[16];
        #pragma unroll
        for (int ks = 0; ks < 8; ks++) {
            xf[2 * ks]     = *reinterpret_cast<const float4*>(xp + ks * 32);
            xf[2 * ks + 1] = *reinterpret_cast<const float4*>(xp + ks * 32 + 4);
        }

        // ---- convert + MFMA: 3 gates x 8 ksteps; A from LDS, B from regs
        floatx4 acc0 = {0.f,0.f,0.f,0.f}, acc1 = {0.f,0.f,0.f,0.f}, acc2 = {0.f,0.f,0.f,0.f};
        #pragma unroll
        for (int ks = 0; ks < 8; ks++) {
            const float4 a = xf[2 * ks], b = xf[2 * ks + 1];
            bf16x8 bfrag;
            bfrag[0] = (__bf16)a.x; bfrag[1] = (__bf16)a.y;
            bfrag[2] = (__bf16)a.z; bfrag[3] = (__bf16)a.w;
            bfrag[4] = (__bf16)b.x; bfrag[5] = (__bf16)b.y;
            bfrag[6] = (__bf16)b.z; bfrag[7] = (__bf16)b.w;
            acc0 = __builtin_amdgcn_mfma_f32_16x16x32_bf16(wlp[(0 * 8 + ks) * 64], bfrag, acc0, 0, 0, 0);
            acc1 = __builtin_amdgcn_mfma_f32_16x16x32_bf16(wlp[(1 * 8 + ks) * 64], bfrag, acc1, 0, 0, 0);
            acc2 = __builtin_amdgcn_mfma_f32_16x16x32_bf16(wlp[(2 * 8 + ks) * 64], bfrag, acc2, 0, 0, 0);
        }

        // ---- GRU epilogue in registers: b = wid*16+lr, h = hbase+lq*4+reg
        float o[4];
        #pragma unroll
        for (int reg = 0; reg < 4; reg++) {
            const float r = sigf(acc0[reg] + gp[reg][0]);
            const float z = sigf(acc1[reg] + gp[reg][1]);
            const float e = __expf(-2.0f * (acc2[reg] + bn[reg] + r * gp[reg][2]));
            const float n = (1.0f - e) / (1.0f + e);
            o[reg] = (1.0f - z) * n + z * gp[reg][3];
        }

        // ---- transpose via per-wave LDS tile, then coalesced 64B stores
        *reinterpret_cast<float4*>(&epi[wid][lr * 20 + lq * 4]) =
            make_float4(o[0], o[1], o[2], o[3]);
        const int m2 = lane >> 2, hs = lane & 3;
        const float4 ov = *reinterpret_cast<const float4*>(
            &epi[wid][m2 * 20 + hs * 4]);

        const int m0 = t * 64 + wid * 16;
        *reinterpret_cast<float4*>(out + (size_t)(m0 + m2) * H_DIM + hbase + hs * 4) = ov;
        if (t == T_DIM - 1)
            *reinterpret_cast<float4*>(out + OUT_MAIN +
                (size_t)(wid * 16 + m2) * H_DIM + hbase + hs * 4) = ov;
    }
}

extern "C" void kernel_launch(void* const* d_in, const int* in_sizes, int n_in,
                              void* d_out, int out_size, void* d_ws, size_t ws_size,
                              hipStream_t stream) {
    const float* x    = (const float*)d_in[0];
    const float* hid  = (const float*)d_in[1];
    const float* w_ih = (const float*)d_in[2];
    const float* w_hh = (const float*)d_in[3];
    const float* b_ih = (const float*)d_in[4];
    const float* b_hh = (const float*)d_in[5];
    float* out = (float*)d_out;

    char* ws = (char*)d_ws;
    unsigned short* wsA = (unsigned short*)ws;              // 393216 B
    float4* ghpack = (float4*)(ws + 393216);                // 262144 B
    float*  biasn  = (float*)(ws + 393216 + 262144);        // 1024 B

    gru_prep<<<161, 256, 0, stream>>>(hid, w_ih, w_hh, b_ih, b_hh, wsA, ghpack, biasn);
    gru_main<<<1024, 256, 0, stream>>>(x, wsA, ghpack, biasn, out);
}